// Round 1
// baseline (79.469 us; speedup 1.0000x reference)
//
#include <hip/hip_runtime.h>

// Butterfly multiply (untied), n=1024, 10 stages, increasing stride, + bias.
//
// Layout: one wave of 64 lanes holds ROWS full rows in registers.
// Element e (0..1023) lives at lane=(e>>2)&63, slot=(e>>8)*4+(e&3):
//   e = i*256 + lane*4 + j   (i,j in 0..3), slot s = i*4+j.
// Stage log_stride ls:
//   ls=0,1  -> pair within j bits      (in-thread, float4 twiddle)
//   ls=2..7 -> pair across lane bits   (__shfl_xor mask 1..32, float2 twiddle)
//   ls=8,9  -> pair within i bits      (in-thread, float4 twiddle)
// Global loads/stores are perfectly coalesced dwordx4 (lane l -> 16B at l*16B).

constexpr int ROWS  = 4;   // rows per wave
constexpr int WAVES = 4;   // waves per block
constexpr int N     = 1024;

__device__ __forceinline__ void pair_update(float (&v)[ROWS][16], int s0, int s1,
                                            const float4 t4)
{
    #pragma unroll
    for (int r = 0; r < ROWS; ++r) {
        const float x0 = v[r][s0], x1 = v[r][s1];
        v[r][s0] = t4.x * x0 + t4.y * x1;
        v[r][s1] = t4.z * x0 + t4.w * x1;
    }
}

template<int LS>
__device__ __forceinline__ void cross_stage(float (&v)[ROWS][16],
                                            const float* __restrict__ tw,
                                            int lane)
{
    constexpr int m = 1 << (LS - 2);              // lane xor mask
    const int ipos = (lane >> (LS - 2)) & 1;      // which half of the pair we are
    const float* __restrict__ base = tw + LS * 2048;
    #pragma unroll
    for (int i = 0; i < 4; ++i) {
        #pragma unroll
        for (int j = 0; j < 4; ++j) {
            const int e    = i * 256 + lane * 4 + j;
            const int pair = ((e >> (LS + 1)) << LS) | (e & ((1 << LS) - 1));
            const float2 t2 = *reinterpret_cast<const float2*>(
                base + (size_t)pair * 4 + ipos * 2);
            const float ta = ipos ? t2.y : t2.x;  // coeff of own value
            const float tb = ipos ? t2.x : t2.y;  // coeff of partner value
            const int s = i * 4 + j;
            #pragma unroll
            for (int r = 0; r < ROWS; ++r) {
                const float own  = v[r][s];
                const float part = __shfl_xor(own, m, 64);
                v[r][s] = ta * own + tb * part;
            }
        }
    }
}

__global__ __launch_bounds__(WAVES * 64)
void butterfly_kernel(const float* __restrict__ x,
                      const float* __restrict__ tw,
                      const float* __restrict__ bias,
                      float* __restrict__ out,
                      int batch)
{
    const int lane = (int)(threadIdx.x & 63u);
    const int wave = (int)(threadIdx.x >> 6u);
    const int row0 = (blockIdx.x * WAVES + wave) * ROWS;
    if (row0 >= batch) return;

    float v[ROWS][16];

    // ---- load: v[r][i*4+j] = x[row][i*256 + lane*4 + j] (coalesced dwordx4)
    #pragma unroll
    for (int r = 0; r < ROWS; ++r) {
        const int row = (row0 + r < batch) ? (row0 + r) : (batch - 1);
        const float4* __restrict__ src =
            reinterpret_cast<const float4*>(x + (size_t)row * N);
        #pragma unroll
        for (int i = 0; i < 4; ++i) {
            const float4 t = src[i * 64 + lane];
            v[r][i*4+0] = t.x; v[r][i*4+1] = t.y;
            v[r][i*4+2] = t.z; v[r][i*4+3] = t.w;
        }
    }

    // ---- ls = 0 (stride 1): slots (i*4+2jj, i*4+2jj+1), pair = i*128+lane*2+jj
    #pragma unroll
    for (int i = 0; i < 4; ++i) {
        #pragma unroll
        for (int jj = 0; jj < 2; ++jj) {
            const int pair = i * 128 + lane * 2 + jj;
            const float4 t4 = *reinterpret_cast<const float4*>(tw + (size_t)pair * 4);
            pair_update(v, i*4 + jj*2, i*4 + jj*2 + 1, t4);
        }
    }

    // ---- ls = 1 (stride 2): slots (i*4+j, i*4+j+2), pair = i*128+lane*2+j
    #pragma unroll
    for (int i = 0; i < 4; ++i) {
        #pragma unroll
        for (int j = 0; j < 2; ++j) {
            const int pair = i * 128 + lane * 2 + j;
            const float4 t4 = *reinterpret_cast<const float4*>(tw + 2048 + (size_t)pair * 4);
            pair_update(v, i*4 + j, i*4 + j + 2, t4);
        }
    }

    // ---- ls = 2..7 (stride 4..128): cross-lane
    cross_stage<2>(v, tw, lane);
    cross_stage<3>(v, tw, lane);
    cross_stage<4>(v, tw, lane);
    cross_stage<5>(v, tw, lane);
    cross_stage<6>(v, tw, lane);
    cross_stage<7>(v, tw, lane);

    // ---- ls = 8 (stride 256): slots (ih*8+j, ih*8+4+j), pair = ih*256+lane*4+j
    #pragma unroll
    for (int ih = 0; ih < 2; ++ih) {
        #pragma unroll
        for (int j = 0; j < 4; ++j) {
            const int pair = ih * 256 + lane * 4 + j;
            const float4 t4 = *reinterpret_cast<const float4*>(tw + 8*2048 + (size_t)pair * 4);
            pair_update(v, ih*8 + j, ih*8 + 4 + j, t4);
        }
    }

    // ---- ls = 9 (stride 512): slots (i*4+j, i*4+8+j), pair = i*256+lane*4+j
    #pragma unroll
    for (int i = 0; i < 2; ++i) {
        #pragma unroll
        for (int j = 0; j < 4; ++j) {
            const int pair = i * 256 + lane * 4 + j;
            const float4 t4 = *reinterpret_cast<const float4*>(tw + 9*2048 + (size_t)pair * 4);
            pair_update(v, i*4 + j, i*4 + 8 + j, t4);
        }
    }

    // ---- bias + store (coalesced dwordx4)
    #pragma unroll
    for (int i = 0; i < 4; ++i) {
        const float4 b4 = *reinterpret_cast<const float4*>(bias + i * 256 + lane * 4);
        #pragma unroll
        for (int r = 0; r < ROWS; ++r) {
            if (row0 + r < batch) {
                float4 o;
                o.x = v[r][i*4+0] + b4.x;
                o.y = v[r][i*4+1] + b4.y;
                o.z = v[r][i*4+2] + b4.z;
                o.w = v[r][i*4+3] + b4.w;
                *reinterpret_cast<float4*>(out + (size_t)(row0 + r) * N + i * 256 + lane * 4) = o;
            }
        }
    }
}

extern "C" void kernel_launch(void* const* d_in, const int* in_sizes, int n_in,
                              void* d_out, int out_size, void* d_ws, size_t ws_size,
                              hipStream_t stream)
{
    (void)n_in; (void)d_ws; (void)ws_size; (void)out_size;
    const float* x    = (const float*)d_in[0];
    const float* tw   = (const float*)d_in[1];
    const float* bias = (const float*)d_in[2];
    float* out        = (float*)d_out;

    const int batch = in_sizes[0] / N;
    const int rows_per_block = WAVES * ROWS;
    const int blocks = (batch + rows_per_block - 1) / rows_per_block;
    hipLaunchKernelGGL(butterfly_kernel, dim3(blocks), dim3(WAVES * 64), 0, stream,
                       x, tw, bias, out, batch);
}